// Round 10
// baseline (409.816 us; speedup 1.0000x reference)
//
#include <hip/hip_runtime.h>

// out[b] = weight[layer_ids[b]] @ z[b] + bias[layer_ids[b]]; all fp32.
// R10: optimized fp32 path (proven numerics from R5). Counting sort, then
// grouped SGEMM with 128x128 block tile, BK=16, k-major LDS (transpose on
// store), 8x8 micro-tile per thread (split 4+4 for float4 LDS reads).
// R5 was LDS-bound (micro 4x4 => 9.1 GB LDS traffic ~ 200us); 8x8 halves
// per-FMA LDS traffic => ~103us LDS floor, 55us VALU floor.

#define HDIM 1024
#define LNUM 16
#define BTOT 4096

constexpr int BM = 128, BN = 128, BK = 16;
constexpr int LDT = BM + 4;  // 132: pad to spread banks for scatter stores

typedef __attribute__((ext_vector_type(4))) float floatx4;

// ---------------------------------------------------------------------------
// Kernel 1: group batch rows by layer (counting sort). Single block. (R5)
// ---------------------------------------------------------------------------
__global__ void group_kernel(const int* __restrict__ layer_ids,
                             int* __restrict__ perm,
                             int* __restrict__ offsets) {
    __shared__ int cnt[LNUM];
    __shared__ int base[LNUM];
    const int t = threadIdx.x;
    if (t < LNUM) cnt[t] = 0;
    __syncthreads();
    for (int b = t; b < BTOT; b += 256)
        atomicAdd(&cnt[layer_ids[b] & (LNUM - 1)], 1);
    __syncthreads();
    if (t == 0) {
        int acc = 0;
        for (int l = 0; l < LNUM; ++l) {
            base[l] = acc;
            offsets[l] = acc;
            acc += cnt[l];
        }
        offsets[LNUM] = acc;
    }
    __syncthreads();
    if (t < LNUM) cnt[t] = 0;
    __syncthreads();
    for (int b = t; b < BTOT; b += 256) {
        int l = layer_ids[b] & (LNUM - 1);
        int p = base[l] + atomicAdd(&cnt[l], 1);
        perm[p] = b;
    }
}

// ---------------------------------------------------------------------------
// Kernel 2: grouped SGEMM, 256 threads, 128x128 tile, BK=16, micro 8x8.
// As[k][m] = z[perm[off+m0+m]][k0+k]; Bs[k][n] = weight[l][n0+n][k0+k].
// Thread (tm=tid&15, tn=tid>>4): rows {tm*4..+3, 64+tm*4..+3},
//                                cols {tn*4..+3, 64+tn*4..+3}.
// ---------------------------------------------------------------------------
__global__ __launch_bounds__(256, 4) void grouped_sgemm_kernel(
    const float* __restrict__ z,
    const float* __restrict__ weight,
    const float* __restrict__ bias,
    const int* __restrict__ perm,
    const int* __restrict__ offsets,
    float* __restrict__ out) {

    const int l = blockIdx.z;
    const int off = offsets[l];
    const int cnt = offsets[l + 1] - off;
    const int m0 = blockIdx.y * BM;
    if (m0 >= cnt) return;  // uniform dead-tile exit
    const int n0 = blockIdx.x * BN;

    __shared__ float As[BK][LDT];
    __shared__ float Bs[BK][LDT];

    const int tid = threadIdx.x;
    const int tm = tid & 15;
    const int tn = tid >> 4;

    // Staging: 512 float4-chunks per matrix per K-tile; 2 per thread.
    // chunk c: mrow = c>>2 (0..127), kq = c&3 (k-quad of 4).
    const float* aS[2];
    const float* bS[2];
    int srow[2], skq[2];
#pragma unroll
    for (int p = 0; p < 2; ++p) {
        int c = tid + p * 256;
        int mrow = c >> 2, kq = c & 3;
        srow[p] = mrow;
        skq[p] = kq;
        int gr = m0 + mrow;
        if (gr > cnt - 1) gr = cnt - 1;  // clamp (stores guarded)
        aS[p] = z + (size_t)perm[off + gr] * HDIM + kq * 4;
        bS[p] = weight + (size_t)l * HDIM * HDIM +
                (size_t)(n0 + mrow) * HDIM + kq * 4;
    }

    float acc[8][8] = {};

    for (int k0 = 0; k0 < HDIM; k0 += BK) {
        floatx4 va[2], vb[2];
#pragma unroll
        for (int p = 0; p < 2; ++p) {
            va[p] = *(const floatx4*)(aS[p] + k0);
            vb[p] = *(const floatx4*)(bS[p] + k0);
        }
        __syncthreads();  // prior iteration's LDS reads complete
#pragma unroll
        for (int p = 0; p < 2; ++p)
#pragma unroll
            for (int e = 0; e < 4; ++e) {
                As[skq[p] * 4 + e][srow[p]] = va[p][e];
                Bs[skq[p] * 4 + e][srow[p]] = vb[p][e];
            }
        __syncthreads();  // staging visible

#pragma unroll
        for (int k = 0; k < BK; ++k) {
            floatx4 a0 = *(const floatx4*)&As[k][tm * 4];
            floatx4 a1 = *(const floatx4*)&As[k][64 + tm * 4];
            floatx4 b0 = *(const floatx4*)&Bs[k][tn * 4];
            floatx4 b1 = *(const floatx4*)&Bs[k][64 + tn * 4];
            float av[8] = {a0[0], a0[1], a0[2], a0[3],
                           a1[0], a1[1], a1[2], a1[3]};
            float bv[8] = {b0[0], b0[1], b0[2], b0[3],
                           b1[0], b1[1], b1[2], b1[3]};
#pragma unroll
            for (int i = 0; i < 8; ++i)
#pragma unroll
                for (int j = 0; j < 8; ++j)
                    acc[i][j] = fmaf(av[i], bv[j], acc[i][j]);
        }
    }

    // Epilogue: two float4 stores per row-half, + bias.
    floatx4 bb[2];
    bb[0] = *(const floatx4*)&bias[l * HDIM + n0 + tn * 4];
    bb[1] = *(const floatx4*)&bias[l * HDIM + n0 + 64 + tn * 4];
#pragma unroll
    for (int ii = 0; ii < 2; ++ii)
#pragma unroll
        for (int i = 0; i < 4; ++i) {
            int gm = m0 + ii * 64 + tm * 4 + i;
            if (gm < cnt) {
                size_t ob = (size_t)perm[off + gm] * HDIM;
#pragma unroll
                for (int jj = 0; jj < 2; ++jj) {
                    floatx4 v;
#pragma unroll
                    for (int j = 0; j < 4; ++j)
                        v[j] = acc[ii * 4 + i][jj * 4 + j] + bb[jj][j];
                    *(floatx4*)&out[ob + n0 + jj * 64 + tn * 4] = v;
                }
            }
        }
}

extern "C" void kernel_launch(void* const* d_in, const int* in_sizes, int n_in,
                              void* d_out, int out_size, void* d_ws, size_t ws_size,
                              hipStream_t stream) {
    const float* z = nullptr;
    const int* layer_ids = nullptr;
    const float* weight = nullptr;
    const float* bias = nullptr;
    for (int i = 0; i < n_in; ++i) {
        switch (in_sizes[i]) {
            case BTOT * HDIM:        z = (const float*)d_in[i]; break;
            case BTOT:               layer_ids = (const int*)d_in[i]; break;
            case LNUM * HDIM * HDIM: weight = (const float*)d_in[i]; break;
            case LNUM * HDIM:        bias = (const float*)d_in[i]; break;
        }
    }
    float* out = (float*)d_out;

    int* perm = (int*)d_ws;       // 4096 ints
    int* offsets = perm + BTOT;   // 17 ints

    group_kernel<<<1, 256, 0, stream>>>(layer_ids, perm, offsets);

    // x = 8 n-tiles, y = 32 m-slots (covers cnt up to 4096 — any skew), z = layer.
    dim3 grid(HDIM / BN, 32, LNUM);
    grouped_sgemm_kernel<<<grid, 256, 0, stream>>>(z, weight, bias, perm,
                                                   offsets, out);
}